// Round 7
// baseline (286.104 us; speedup 1.0000x reference)
//
#include <hip/hip_runtime.h>

// Problem constants (fixed by the reference)
#define BB 2
#define LL 2048
#define SS 2048
#define HH 16
#define EE 64
#define HE (HH*EE)          // fp32 elements per token row: 1024
#define BL 128              // l-rows per band
#define TS 64               // s-cols per tile
#define NT2 32              // 64-col tiles across S
#define SCALEF 0.125f       // 1/sqrt(64)
#define NEGBIG (-1e30f)     // -inf stand-in; exp underflows to exact 0

typedef __bf16 bf8 __attribute__((ext_vector_type(8)));
typedef float f4v __attribute__((ext_vector_type(4)));
typedef unsigned int u32;
typedef unsigned short u16;

// d_out layout (fp32 elements): V | A | entropy, concatenated in return order
#define V_ELEMS  ((size_t)BB*LL*HH*EE)              // 4,194,304
#define A_BASE   (V_ELEMS)
#define ENT_BASE (A_BASE + (size_t)BB*HH*LL*SS)     // + 134,217,728

__device__ __forceinline__ u16 bfb(float f) {  // fp32 -> bf16 RNE
    u32 u = __builtin_bit_cast(u32, f);
    return (u16)((u + 0x7fffu + ((u >> 16) & 1u)) >> 16);
}
__device__ __forceinline__ float bf2f(u32 lo16) {  // bf16 bits (low half) -> fp32, exact
    return __builtin_bit_cast(float, lo16 << 16);
}
// XOR swizzle on byte-addr bits 4-6: fixes 128B-row-stride LDS bank conflicts (G4/T2)
__device__ __forceinline__ int swz8(int r) { return (((r) & 7) ^ (((r) >> 3) & 7)) << 4; }

__device__ __forceinline__ f4v mfma16(bf8 a, bf8 b, f4v c) {
    return __builtin_amdgcn_mfma_f32_16x16x32_bf16(a, b, c, 0, 0, 0);
}
// Masks may arrive as 1-byte bool or 4-byte int32 — runtime-detected.
__device__ __forceinline__ int maskv(const void* p, int i, int isB) {
    return isB ? (int)((const unsigned char*)p)[i] : ((const int*)p)[i];
}

// Stage a 128x64 fp32 tile (row stride HE) into LDS as bf16 [128][64] swizzled.
// 512 threads: r = tid>>2 (0..127), seg = tid&3 (16 cols each).
__device__ __forceinline__ void stage128x64(const float* __restrict__ src,
                                            char* lds, int tid) {
    const int r = tid >> 2, seg = tid & 3;
    const float* rp = src + (size_t)r * HE + seg * 16;
    float4 f0 = *(const float4*)(rp + 0);
    float4 f1 = *(const float4*)(rp + 4);
    float4 f2 = *(const float4*)(rp + 8);
    float4 f3 = *(const float4*)(rp + 12);
    uint4 w0, w1;
    w0.x = bfb(f0.x) | ((u32)bfb(f0.y) << 16);
    w0.y = bfb(f0.z) | ((u32)bfb(f0.w) << 16);
    w0.z = bfb(f1.x) | ((u32)bfb(f1.y) << 16);
    w0.w = bfb(f1.z) | ((u32)bfb(f1.w) << 16);
    w1.x = bfb(f2.x) | ((u32)bfb(f2.y) << 16);
    w1.y = bfb(f2.z) | ((u32)bfb(f2.w) << 16);
    w1.z = bfb(f3.x) | ((u32)bfb(f3.y) << 16);
    w1.w = bfb(f3.z) | ((u32)bfb(f3.w) << 16);
    const int base = r * 128 + seg * 32;
    *(uint4*)(void*)(lds + ((base +  0) ^ swz8(r))) = w0;
    *(uint4*)(void*)(lds + ((base + 16) ^ swz8(r))) = w1;
}
// Stage a 64x64 fp32 K tile into LDS (512 threads: kr = tid>>3, 8-col segs).
__device__ __forceinline__ void stageK64(const float* __restrict__ src,
                                         char* lds, int tid) {
    const int kr = tid >> 3, seg = tid & 7;
    const float* s = src + (size_t)kr * HE + seg * 8;
    float4 f0 = *(const float4*)(s);
    float4 f1 = *(const float4*)(s + 4);
    uint4 wv;
    wv.x = bfb(f0.x) | ((u32)bfb(f0.y) << 16);
    wv.y = bfb(f0.z) | ((u32)bfb(f0.w) << 16);
    wv.z = bfb(f1.x) | ((u32)bfb(f1.y) << 16);
    wv.w = bfb(f1.z) | ((u32)bfb(f1.w) << 16);
    *(uint4*)(void*)(lds + ((kr * 128 + seg * 16) ^ swz8(kr))) = wv;
}

// One block = (b, h, band-pair): bands {pair, 15-pair}, 128 q-rows each —
// every block runs exactly 34 causal 64-col tiles (balanced). 8 waves, each
// owns 16 q-rows. Pass 1: logsumexp C = M+lnD + entropy (C in registers,
// tile-level rescale). Pass 2: recompute QK^T (bit-identical), P -> LDS
// (bf16), PV MFMA, then stream A out of LDS as full-line fp32 stores.
__global__ __launch_bounds__(512) void k_fused(
    const float* __restrict__ Qg, const float* __restrict__ Kg, const float* __restrict__ Vg,
    const void* __restrict__ mk, const void* __restrict__ mq,
    float* __restrict__ outF)
{
    __shared__ __align__(16) char ldsA[16384];   // Q-stage [128][64]bf16, then P [128][64]bf16
    __shared__ __align__(16) char ldsK[8192];    // K tile [64 s][64 e] bf16
    __shared__ __align__(16) char ldsVT[8192];   // V^T tile [64 e][64 s] bf16
    __shared__ float ldsKM[TS];
    __shared__ int sFlag;

    const int blk = blockIdx.x;
    const int bh  = (blk & 7) + (((blk >> 3) & 3) << 3);  // XCD-major: 4 (b,h) panels per XCD L2
    const int pair = blk >> 5;
    const int b = bh >> 4, h = bh & 15;
    const int tid = threadIdx.x;
    const int w = tid >> 6, lane = tid & 63, g = lane >> 4, le = lane & 15;

    // ---- mask element-width detection (1B bool vs 4B int32), first 4KB of mk ----
    int isB;
    {
        const unsigned char* c = (const unsigned char*)mk;
        unsigned acc = 0;
        #pragma unroll
        for (int j = 0; j < 8; ++j) {
            const int off = tid + j * 512;
            if (off & 3) acc |= c[off];   // int32 0/1 data: all these bytes are 0
        }
        if (tid == 0) sFlag = 0;
        __syncthreads();
        if (acc) atomicOr(&sFlag, 1);
        __syncthreads();
        isB = sFlag;
    }

    const float* Qb = Qg + (size_t)b * LL * HE + h * EE;
    const float* Kb = Kg + (size_t)b * SS * HE + h * EE;
    const float* Vb = Vg + (size_t)b * SS * HE + h * EE;

    for (int bi = 0; bi < 2; ++bi) {
        const int band = bi ? (15 - pair) : pair;
        const int l0 = band * BL;
        const int lbase = l0 + w * 16 + g * 4;   // this lane's 4 C-layout rows
        const int ntile = 2 * (band + 1);        // causal 64-col tiles

        // ---- stage Q tile [128][64] -> ldsA, grab fragments ----
        stage128x64(Qb + (size_t)l0 * HE, ldsA, tid);
        __syncthreads();
        const int qr = w * 16 + le;   // A-frag: row = lane&15
        bf8 qf0 = *(const bf8*)(void*)(ldsA + ((qr * 128 +  0 + g * 16) ^ swz8(qr)));
        bf8 qf1 = *(const bf8*)(void*)(ldsA + ((qr * 128 + 64 + g * 16) ^ swz8(qr)));
        __syncthreads();   // ldsA free for P after this

        // ================= PASS 1: per-row M, D, T =================
        float M[4], D[4], T[4];
        #pragma unroll
        for (int r = 0; r < 4; ++r) { M[r] = NEGBIG; D[r] = 0.f; T[r] = 0.f; }

        for (int st = 0; st < ntile; ++st) {
            const int s0 = st * TS;
            stageK64(Kb + (size_t)s0 * HE, ldsK, tid);
            if (tid < TS) ldsKM[tid] = maskv(mk, b * SS + s0 + tid, isB) ? NEGBIG : 0.f;
            __syncthreads();

            f4v acc[4];
            float tm[4] = {NEGBIG, NEGBIG, NEGBIG, NEGBIG};
            #pragma unroll
            for (int cb = 0; cb < 4; ++cb) {
                const int sr = cb * 16 + le;     // B-frag: col = lane&15
                bf8 k0 = *(const bf8*)(void*)(ldsK + ((sr * 128 +  0 + g * 16) ^ swz8(sr)));
                bf8 k1 = *(const bf8*)(void*)(ldsK + ((sr * 128 + 64 + g * 16) ^ swz8(sr)));
                f4v a = {0.f, 0.f, 0.f, 0.f};
                a = mfma16(qf0, k0, a);
                a = mfma16(qf1, k1, a);
                const float km = ldsKM[cb * 16 + le];
                const int s = s0 + cb * 16 + le;
                #pragma unroll
                for (int r = 0; r < 4; ++r) {
                    float z = a[r] * SCALEF + km;       // scale*(score + m_k)
                    if (s > lbase + r) z = NEGBIG;      // causal (pos == arange)
                    acc[cb][r] = z;
                    tm[r] = fmaxf(tm[r], z);
                }
            }
            // tile-level rescale: one shared max per row-tile, 1 exp per element
            #pragma unroll
            for (int r = 0; r < 4; ++r) {
                #pragma unroll
                for (int msk = 1; msk < 16; msk <<= 1)
                    tm[r] = fmaxf(tm[r], __shfl_xor(tm[r], msk));
                const float mn  = fmaxf(M[r], tm[r]);
                const float fre = __expf(M[r] - mn);    // 0 when jumping off -1e30
                float ed = 0.f, et = 0.f;
                #pragma unroll
                for (int cb = 0; cb < 4; ++cb) {
                    const float z = acc[cb][r];
                    const float e = __expf(z - mn);     // all-masked-prefix junk self-wipes via fre
                    ed += e; et += e * z;
                }
                D[r] = D[r] * fre + ed;
                T[r] = T[r] * fre + et;
                M[r] = mn;
            }
            __syncthreads();
        }

        // butterfly-merge over the 16-lane group; everyone ends with full-row stats
        float C[4];
        #pragma unroll
        for (int r = 0; r < 4; ++r) {
            #pragma unroll
            for (int msk = 1; msk < 16; msk <<= 1) {
                const float Mo = __shfl_xor(M[r], msk);
                const float Do = __shfl_xor(D[r], msk);
                const float To = __shfl_xor(T[r], msk);
                const float mn = fmaxf(M[r], Mo);
                const float fa = __expf(M[r] - mn);
                const float fb = __expf(Mo  - mn);
                D[r] = D[r] * fa + Do * fb;
                T[r] = T[r] * fa + To * fb;
                M[r] = mn;
            }
            const int l = lbase + r;
            const bool valid = (M[r] > -1e29f) && (maskv(mq, b * LL + l, isB) == 0);
            C[r] = valid ? (M[r] + __logf(D[r])) : 1e30f;     // p = exp(z - C); dead rows -> p = 0
            const float ent = valid ? (C[r] - T[r] / D[r]) : 0.f;
            if (le == 0) outF[ENT_BASE + (size_t)bh * LL + l] = ent;
        }

        // ================= PASS 2: P -> LDS, O = P·V, A streamed from LDS =================
        f4v O[4];
        #pragma unroll
        for (int eb = 0; eb < 4; ++eb) O[eb] = (f4v){0.f, 0.f, 0.f, 0.f};

        for (int st = 0; st < ntile; ++st) {
            const int s0 = st * TS;
            stageK64(Kb + (size_t)s0 * HE, ldsK, tid);
            {   // V^T tile: VT[e][s], s-pairs packed per u32 (round-4 verified stager:
                // rp = tid>>4 in 0..31 covers 64 s-rows in pairs; ei = tid&15, 4 e's each)
                const int rp = tid >> 4, ei = tid & 15;
                const float* v0p = Vb + (size_t)(s0 + 2 * rp) * HE + ei * 4;
                const float* v1p = v0p + HE;
                float4 va = *(const float4*)v0p;
                float4 vb2 = *(const float4*)v1p;
                const float* pa_ = &va.x;
                const float* pb_ = &vb2.x;
                #pragma unroll
                for (int i = 0; i < 4; ++i) {
                    const int e = ei * 4 + i;
                    const u32 pk = (u32)bfb(pa_[i]) | ((u32)bfb(pb_[i]) << 16);
                    *(u32*)(void*)(ldsVT + ((e * 128 + rp * 4) ^ swz8(e))) = pk;
                }
            }
            if (tid < TS) ldsKM[tid] = maskv(mk, b * SS + s0 + tid, isB) ? NEGBIG : 0.f;
            __syncthreads();

            // QK^T — identical instruction sequence to pass 1 -> bit-identical z
            f4v acc[4];
            #pragma unroll
            for (int cb = 0; cb < 4; ++cb) {
                const int sr = cb * 16 + le;
                bf8 k0 = *(const bf8*)(void*)(ldsK + ((sr * 128 +  0 + g * 16) ^ swz8(sr)));
                bf8 k1 = *(const bf8*)(void*)(ldsK + ((sr * 128 + 64 + g * 16) ^ swz8(sr)));
                f4v a = {0.f, 0.f, 0.f, 0.f};
                a = mfma16(qf0, k0, a);
                a = mfma16(qf1, k1, a);
                acc[cb] = a;
            }
            // P -> LDS only (bf16); A leaves via the LDS streaming store below
            #pragma unroll
            for (int cb = 0; cb < 4; ++cb) {
                const float km = ldsKM[cb * 16 + le];
                const int s = s0 + cb * 16 + le;
                #pragma unroll
                for (int r = 0; r < 4; ++r) {
                    float z = acc[cb][r] * SCALEF + km;
                    if (s > lbase + r) z = NEGBIG;
                    const float p = __expf(z - C[r]);   // exact 0 for masked/causal/dead
                    const int row = w * 16 + g * 4 + r;
                    *(u16*)(void*)(ldsA + ((row * 128 + (cb * 16 + le) * 2) ^ swz8(row))) = bfb(p);
                }
            }
            __syncthreads();   // P complete

            // PV: A-frag rows = lane&15
            const int prow = w * 16 + le;
            #pragma unroll
            for (int kkb = 0; kkb < 2; ++kkb) {
                bf8 pa = *(const bf8*)(void*)(ldsA + ((prow * 128 + kkb * 64 + g * 16) ^ swz8(prow)));
                #pragma unroll
                for (int eb = 0; eb < 4; ++eb) {
                    const int e = eb * 16 + le;
                    bf8 vb = *(const bf8*)(void*)(ldsVT + ((e * 128 + kkb * 64 + g * 16) ^ swz8(e)));
                    O[eb] = mfma16(pa, vb, O[eb]);
                }
            }
            // A-store streamed from LDS: 16 bf16 -> 16 fp32 per lane, 4 lanes
            // cover a 256B-contiguous row segment -> full-line writes.
            {
                const int r = tid >> 2, seg = tid & 3;
                uint4 w0 = *(const uint4*)(void*)(ldsA + ((r * 128 + seg * 32 +  0) ^ swz8(r)));
                uint4 w1 = *(const uint4*)(void*)(ldsA + ((r * 128 + seg * 32 + 16) ^ swz8(r)));
                float* dst = &outF[A_BASE + ((size_t)bh * LL + (l0 + r)) * SS + s0 + seg * 16];
                float4 o0 = {bf2f(w0.x & 0xffffu), bf2f(w0.x >> 16), bf2f(w0.y & 0xffffu), bf2f(w0.y >> 16)};
                float4 o1 = {bf2f(w0.z & 0xffffu), bf2f(w0.z >> 16), bf2f(w0.w & 0xffffu), bf2f(w0.w >> 16)};
                float4 o2 = {bf2f(w1.x & 0xffffu), bf2f(w1.x >> 16), bf2f(w1.y & 0xffffu), bf2f(w1.y >> 16)};
                float4 o3 = {bf2f(w1.z & 0xffffu), bf2f(w1.z >> 16), bf2f(w1.w & 0xffffu), bf2f(w1.w >> 16)};
                *(float4*)(dst +  0) = o0;
                *(float4*)(dst +  4) = o1;
                *(float4*)(dst +  8) = o2;
                *(float4*)(dst + 12) = o3;
            }
            __syncthreads();   // P reads done before next tile's stores
        }

        // zero-fill strictly-upper-triangle tiles (clear poison)
        {
            const int r = tid >> 2, cseg = tid & 3;
            const float4 zz = {0.f, 0.f, 0.f, 0.f};
            for (int st = ntile; st < NT2; ++st) {
                float* dst = &outF[A_BASE + ((size_t)bh * LL + (l0 + r)) * SS + st * TS + cseg * 16];
                #pragma unroll
                for (int i = 0; i < 4; ++i) *(float4*)(dst + i * 4) = zz;
            }
        }

        // V output (B,L,H,E) fp32
        #pragma unroll
        for (int eb = 0; eb < 4; ++eb) {
            #pragma unroll
            for (int r = 0; r < 4; ++r) {
                const int l = lbase + r;
                outF[((size_t)(b * LL + l) * HH + h) * EE + eb * 16 + le] = O[eb][r];
            }
        }
        __syncthreads();   // ldsA/ldsK reused next band
    }
}

extern "C" void kernel_launch(void* const* d_in, const int* in_sizes, int n_in,
                              void* d_out, int out_size, void* d_ws, size_t ws_size,
                              hipStream_t stream) {
    const float* Q = (const float*)d_in[0];   // fp32
    const float* K = (const float*)d_in[1];
    const float* V = (const float*)d_in[2];
    const void* mk = d_in[3];                 // mask_miss_k (B,S,1), nonzero = missing
    const void* mq = d_in[4];                 // mask_miss_q (B,L,1)
    // d_in[5] = pos (arange -> causal is s > l), d_in[6] = causal_mask (always 1)
    float* outF = (float*)d_out;              // fp32: V | A | entropy

    dim3 blk(512), grid(BB * HH * 8);         // 256 blocks, 8 waves each
    hipLaunchKernelGGL(k_fused, grid, blk, 0, stream, Q, K, V, mk, mq, outF);
}

// Round 8
// 236.677 us; speedup vs baseline: 1.2088x; 1.2088x over previous
//
#include <hip/hip_runtime.h>

// Problem constants (fixed by the reference)
#define BB 2
#define LL 2048
#define SS 2048
#define HH 16
#define EE 64
#define HE (HH*EE)          // fp32 elements per token row: 1024
#define BL 128              // l-rows per band
#define TS 64               // s-cols per tile
#define NT2 32              // 64-col tiles across S
#define SCALEF 0.125f       // 1/sqrt(64)
#define NEGBIG (-1e30f)     // -inf stand-in; exp underflows to exact 0

typedef __bf16 bf8 __attribute__((ext_vector_type(8)));
typedef float f4v __attribute__((ext_vector_type(4)));
typedef unsigned int u32;
typedef unsigned short u16;

// d_out layout (fp32 elements): V | A | entropy, concatenated in return order
#define V_ELEMS  ((size_t)BB*LL*HH*EE)              // 4,194,304
#define A_BASE   (V_ELEMS)
#define ENT_BASE (A_BASE + (size_t)BB*HH*LL*SS)     // + 134,217,728

__device__ __forceinline__ u16 bfb(float f) {  // fp32 -> bf16 RNE
    u32 u = __builtin_bit_cast(u32, f);
    return (u16)((u + 0x7fffu + ((u >> 16) & 1u)) >> 16);
}
// XOR swizzle on byte-addr bits 4-6: fixes 128B-row-stride LDS bank conflicts (G4/T2)
__device__ __forceinline__ int swz8(int r) { return (((r) & 7) ^ (((r) >> 3) & 7)) << 4; }

__device__ __forceinline__ f4v mfma16(bf8 a, bf8 b, f4v c) {
    return __builtin_amdgcn_mfma_f32_16x16x32_bf16(a, b, c, 0, 0, 0);
}
// Masks may arrive as 1-byte bool or 4-byte int32 — runtime-detected.
__device__ __forceinline__ int maskv(const void* p, int i, int isB) {
    return isB ? (int)((const unsigned char*)p)[i] : ((const int*)p)[i];
}
// LDS-only barrier: waits ds ops, does NOT drain vmcnt — prefetched global
// loads stay in flight across it (T14 / 8-phase pattern). The asm memory
// clobbers pin LDS ops and load-issue order around the s_barrier.
__device__ __forceinline__ void barrier_lds() {
    asm volatile("s_waitcnt lgkmcnt(0)" ::: "memory");
    __builtin_amdgcn_s_barrier();
    asm volatile("" ::: "memory");
}
__device__ __forceinline__ uint4 pack8(float4 f0, float4 f1) {  // 8 fp32 -> 8 bf16
    uint4 wv;
    wv.x = bfb(f0.x) | ((u32)bfb(f0.y) << 16);
    wv.y = bfb(f0.z) | ((u32)bfb(f0.w) << 16);
    wv.z = bfb(f1.x) | ((u32)bfb(f1.y) << 16);
    wv.w = bfb(f1.z) | ((u32)bfb(f1.w) << 16);
    return wv;
}

// Stage a 128x64 fp32 tile (row stride HE) into LDS as bf16 [128][64] swizzled.
__device__ __forceinline__ void stage128x64(const float* __restrict__ src,
                                            char* lds, int tid) {
    const int r = tid >> 2, seg = tid & 3;
    const float* rp = src + (size_t)r * HE + seg * 16;
    float4 f0 = *(const float4*)(rp + 0);
    float4 f1 = *(const float4*)(rp + 4);
    float4 f2 = *(const float4*)(rp + 8);
    float4 f3 = *(const float4*)(rp + 12);
    const int base = r * 128 + seg * 32;
    *(uint4*)(void*)(lds + ((base +  0) ^ swz8(r))) = pack8(f0, f1);
    *(uint4*)(void*)(lds + ((base + 16) ^ swz8(r))) = pack8(f2, f3);
}

// One block = (b, h, band-pair): bands {pair, 15-pair}, 128 q-rows each —
// exactly 34 causal 64-col tiles per pass (balanced). 8 waves; wave owns 16
// q-rows. Pass 1: logsumexp C=M+lnD + entropy (C in registers, tile-level
// rescale). Pass 2: recompute QK^T (bit-identical), A=exp(z-C) direct fp32
// stores, P->LDS (bf16), O = P·V via MFMA. K/V tiles are register-prefetched
// one tile ahead; in-loop barriers are lgkm-only so prefetch loads stay in
// flight across them (T14).
__global__ __launch_bounds__(512) void k_fused(
    const float* __restrict__ Qg, const float* __restrict__ Kg, const float* __restrict__ Vg,
    const void* __restrict__ mk, const void* __restrict__ mq,
    float* __restrict__ outF)
{
    __shared__ __align__(16) char ldsA[16384];   // Q-stage [128][64]bf16, then P [128][64]bf16
    __shared__ __align__(16) char ldsK[8192];    // K tile [64 s][64 e] bf16
    __shared__ __align__(16) char ldsVT[8192];   // V^T tile [64 e][64 s] bf16
    __shared__ float ldsKM[SS];                  // full k-mask row as additive bias (8KB)
    __shared__ int sFlag;

    const int blk = blockIdx.x;
    const int bh  = (blk & 7) + (((blk >> 3) & 3) << 3);  // XCD-major: 4 (b,h) panels per XCD L2
    const int pair = blk >> 5;
    const int b = bh >> 4, h = bh & 15;
    const int tid = threadIdx.x;
    const int w = tid >> 6, lane = tid & 63, g = lane >> 4, le = lane & 15;

    // ---- mask element-width detection (1B bool vs 4B int32), first 4KB of mk ----
    int isB;
    {
        const unsigned char* c = (const unsigned char*)mk;
        unsigned acc = 0;
        #pragma unroll
        for (int j = 0; j < 8; ++j) {
            const int off = tid + j * 512;
            if (off & 3) acc |= c[off];   // int32 0/1 data: all these bytes are 0
        }
        if (tid == 0) sFlag = 0;
        __syncthreads();
        if (acc) atomicOr(&sFlag, 1);
        __syncthreads();
        isB = sFlag;
    }
    // ---- preload the whole k-mask row once (removes per-tile mask staging) ----
    for (int i = tid; i < SS; i += 512)
        ldsKM[i] = maskv(mk, b * SS + i, isB) ? NEGBIG : 0.f;

    const float* Qb = Qg + (size_t)b * LL * HE + h * EE;
    const float* Kb = Kg + (size_t)b * SS * HE + h * EE;
    const float* Vb = Vg + (size_t)b * SS * HE + h * EE;

    // per-thread staging geometry (constant across tiles)
    const int kr = tid >> 3, ksg = tid & 7;             // K stager: 64 rows x 8 segs
    const float* kbase = Kb + (size_t)kr * HE + ksg * 8;
    const int vrp = tid >> 4, vei = tid & 15;           // V^T stager: 32 row-pairs x 16 e-quads
    const float* vbase = Vb + (size_t)(2 * vrp) * HE + vei * 4;

    for (int bi = 0; bi < 2; ++bi) {
        const int band = bi ? (15 - pair) : pair;
        const int l0 = band * BL;
        const int lbase = l0 + w * 16 + g * 4;   // this lane's 4 C-layout rows
        const int ntile = 2 * (band + 1);        // causal 64-col tiles

        // ---- stage Q tile [128][64] -> ldsA, grab fragments ----
        stage128x64(Qb + (size_t)l0 * HE, ldsA, tid);
        __syncthreads();
        const int qr = w * 16 + le;   // A-frag: row = lane&15
        bf8 qf0 = *(const bf8*)(void*)(ldsA + ((qr * 128 +  0 + g * 16) ^ swz8(qr)));
        bf8 qf1 = *(const bf8*)(void*)(ldsA + ((qr * 128 + 64 + g * 16) ^ swz8(qr)));
        barrier_lds();   // ldsA free for P after this

        // ================= PASS 1: per-row M, D, T =================
        float M[4], D[4], T[4];
        #pragma unroll
        for (int r = 0; r < 4; ++r) { M[r] = NEGBIG; D[r] = 0.f; T[r] = 0.f; }

        float4 ka = *(const float4*)(kbase);         // prologue: tile 0 in regs
        float4 kb2 = *(const float4*)(kbase + 4);

        for (int st = 0; st < ntile; ++st) {
            const int s0 = st * TS;
            // write current K tile from regs, then issue next tile's loads
            *(uint4*)(void*)(ldsK + ((kr * 128 + ksg * 16) ^ swz8(kr))) = pack8(ka, kb2);
            if (st + 1 < ntile) {
                const float* kp = kbase + (size_t)((st + 1) * TS) * HE;
                ka = *(const float4*)(kp);
                kb2 = *(const float4*)(kp + 4);
            }
            barrier_lds();   // K tile visible; prefetch stays in flight

            f4v acc[4];
            float tm[4] = {NEGBIG, NEGBIG, NEGBIG, NEGBIG};
            #pragma unroll
            for (int cb = 0; cb < 4; ++cb) {
                const int sr = cb * 16 + le;     // B-frag: col = lane&15
                bf8 k0 = *(const bf8*)(void*)(ldsK + ((sr * 128 +  0 + g * 16) ^ swz8(sr)));
                bf8 k1 = *(const bf8*)(void*)(ldsK + ((sr * 128 + 64 + g * 16) ^ swz8(sr)));
                f4v a = {0.f, 0.f, 0.f, 0.f};
                a = mfma16(qf0, k0, a);
                a = mfma16(qf1, k1, a);
                const float km = ldsKM[s0 + cb * 16 + le];
                const int s = s0 + cb * 16 + le;
                #pragma unroll
                for (int r = 0; r < 4; ++r) {
                    float z = a[r] * SCALEF + km;       // scale*(score + m_k)
                    if (s > lbase + r) z = NEGBIG;      // causal (pos == arange)
                    acc[cb][r] = z;
                    tm[r] = fmaxf(tm[r], z);
                }
            }
            // tile-level rescale: one shared max per row-tile, 1 exp per element
            #pragma unroll
            for (int r = 0; r < 4; ++r) {
                #pragma unroll
                for (int msk = 1; msk < 16; msk <<= 1)
                    tm[r] = fmaxf(tm[r], __shfl_xor(tm[r], msk));
                const float mn  = fmaxf(M[r], tm[r]);
                const float fre = __expf(M[r] - mn);    // 0 when jumping off -1e30
                float ed = 0.f, et = 0.f;
                #pragma unroll
                for (int cb = 0; cb < 4; ++cb) {
                    const float z = acc[cb][r];
                    const float e = __expf(z - mn);
                    ed += e; et += e * z;
                }
                D[r] = D[r] * fre + ed;
                T[r] = T[r] * fre + et;
                M[r] = mn;
            }
            barrier_lds();   // all K reads done before next overwrite
        }

        // butterfly-merge over the 16-lane group; everyone ends with full-row stats
        float C[4];
        #pragma unroll
        for (int r = 0; r < 4; ++r) {
            #pragma unroll
            for (int msk = 1; msk < 16; msk <<= 1) {
                const float Mo = __shfl_xor(M[r], msk);
                const float Do = __shfl_xor(D[r], msk);
                const float To = __shfl_xor(T[r], msk);
                const float mn = fmaxf(M[r], Mo);
                const float fa = __expf(M[r] - mn);
                const float fb = __expf(Mo  - mn);
                D[r] = D[r] * fa + Do * fb;
                T[r] = T[r] * fa + To * fb;
                M[r] = mn;
            }
            const int l = lbase + r;
            const bool valid = (M[r] > -1e29f) && (maskv(mq, b * LL + l, isB) == 0);
            C[r] = valid ? (M[r] + __logf(D[r])) : 1e30f;     // p = exp(z - C); dead rows -> p = 0
            const float ent = valid ? (C[r] - T[r] / D[r]) : 0.f;
            if (le == 0) outF[ENT_BASE + (size_t)bh * LL + l] = ent;
        }

        // ================= PASS 2: A (fp32 direct) + O = A·V =================
        f4v O[4];
        #pragma unroll
        for (int eb = 0; eb < 4; ++eb) O[eb] = (f4v){0.f, 0.f, 0.f, 0.f};

        ka  = *(const float4*)(kbase);               // prologue: tile 0
        kb2 = *(const float4*)(kbase + 4);
        float4 va  = *(const float4*)(vbase);
        float4 vb2 = *(const float4*)(vbase + HE);

        for (int st = 0; st < ntile; ++st) {
            const int s0 = st * TS;
            // write current K + V^T tiles from regs
            *(uint4*)(void*)(ldsK + ((kr * 128 + ksg * 16) ^ swz8(kr))) = pack8(ka, kb2);
            {
                const float* pa_ = &va.x;
                const float* pb_ = &vb2.x;
                #pragma unroll
                for (int i = 0; i < 4; ++i) {
                    const int e = vei * 4 + i;
                    const u32 pk = (u32)bfb(pa_[i]) | ((u32)bfb(pb_[i]) << 16);
                    *(u32*)(void*)(ldsVT + ((e * 128 + vrp * 4) ^ swz8(e))) = pk;
                }
            }
            if (st + 1 < ntile) {   // issue next tile's K+V loads (fly across barriers)
                const float* kp = kbase + (size_t)((st + 1) * TS) * HE;
                const float* vp = vbase + (size_t)((st + 1) * TS) * HE;
                ka  = *(const float4*)(kp);
                kb2 = *(const float4*)(kp + 4);
                va  = *(const float4*)(vp);
                vb2 = *(const float4*)(vp + HE);
            }
            barrier_lds();

            // QK^T — identical instruction sequence to pass 1 -> bit-identical z
            f4v acc[4];
            #pragma unroll
            for (int cb = 0; cb < 4; ++cb) {
                const int sr = cb * 16 + le;
                bf8 k0 = *(const bf8*)(void*)(ldsK + ((sr * 128 +  0 + g * 16) ^ swz8(sr)));
                bf8 k1 = *(const bf8*)(void*)(ldsK + ((sr * 128 + 64 + g * 16) ^ swz8(sr)));
                f4v a = {0.f, 0.f, 0.f, 0.f};
                a = mfma16(qf0, k0, a);
                a = mfma16(qf1, k1, a);
                acc[cb] = a;
            }
            // P -> LDS (bf16 MFMA operand) and A -> global (fp32, direct from reg)
            #pragma unroll
            for (int cb = 0; cb < 4; ++cb) {
                const float km = ldsKM[s0 + cb * 16 + le];
                const int s = s0 + cb * 16 + le;
                #pragma unroll
                for (int r = 0; r < 4; ++r) {
                    float z = acc[cb][r] * SCALEF + km;
                    if (s > lbase + r) z = NEGBIG;
                    const float p = __expf(z - C[r]);   // exact 0 for masked/causal/dead
                    const int row = w * 16 + g * 4 + r;
                    *(u16*)(void*)(ldsA + ((row * 128 + (cb * 16 + le) * 2) ^ swz8(row))) = bfb(p);
                    outF[A_BASE + ((size_t)bh * LL + (l0 + row)) * SS + s] = p;
                }
            }
            barrier_lds();   // P complete

            // PV: A-frag rows = lane&15
            const int prow = w * 16 + le;
            #pragma unroll
            for (int kkb = 0; kkb < 2; ++kkb) {
                bf8 pa = *(const bf8*)(void*)(ldsA + ((prow * 128 + kkb * 64 + g * 16) ^ swz8(prow)));
                #pragma unroll
                for (int eb = 0; eb < 4; ++eb) {
                    const int e = eb * 16 + le;
                    bf8 vb = *(const bf8*)(void*)(ldsVT + ((e * 128 + kkb * 64 + g * 16) ^ swz8(e)));
                    O[eb] = mfma16(pa, vb, O[eb]);
                }
            }
            barrier_lds();   // P/V^T reads done before next tile's writes
        }

        // zero-fill strictly-upper-triangle tiles (clear poison)
        {
            const int r = tid >> 2, cseg = tid & 3;
            const float4 zz = {0.f, 0.f, 0.f, 0.f};
            for (int st = ntile; st < NT2; ++st) {
                float* dst = &outF[A_BASE + ((size_t)bh * LL + (l0 + r)) * SS + st * TS + cseg * 16];
                #pragma unroll
                for (int i = 0; i < 4; ++i) *(float4*)(dst + i * 4) = zz;
            }
        }

        // V output (B,L,H,E) fp32
        #pragma unroll
        for (int eb = 0; eb < 4; ++eb) {
            #pragma unroll
            for (int r = 0; r < 4; ++r) {
                const int l = lbase + r;
                outF[((size_t)(b * LL + l) * HH + h) * EE + eb * 16 + le] = O[eb][r];
            }
        }
        __syncthreads();   // band end: full drain before ldsA reuse
    }
}

extern "C" void kernel_launch(void* const* d_in, const int* in_sizes, int n_in,
                              void* d_out, int out_size, void* d_ws, size_t ws_size,
                              hipStream_t stream) {
    const float* Q = (const float*)d_in[0];   // fp32
    const float* K = (const float*)d_in[1];
    const float* V = (const float*)d_in[2];
    const void* mk = d_in[3];                 // mask_miss_k (B,S,1), nonzero = missing
    const void* mq = d_in[4];                 // mask_miss_q (B,L,1)
    // d_in[5] = pos (arange -> causal is s > l), d_in[6] = causal_mask (always 1)
    float* outF = (float*)d_out;              // fp32: V | A | entropy

    dim3 blk(512), grid(BB * HH * 8);         // 256 blocks, 8 waves each
    hipLaunchKernelGGL(k_fused, grid, blk, 0, stream, Q, K, V, mk, mq, outF);
}